// Round 1
// baseline (180.937 us; speedup 1.0000x reference)
//
#include <hip/hip_runtime.h>
#include <stdint.h>
#include <stddef.h>

// gcnmask: N=50000, DEG=16, F=128. Edges grouped by dst (dst = e/16) -> no atomics.
// R9: R8 numerics, but edge_k/out_k gather loops restructured for MLP: all 16 edges'
//     gather loads issued into register arrays BEFORE compute (load-all-then-compute),
//     #pragma unroll 1 on the pr loop to bound pressure to one batch. R8's VGPR=36
//     serialized the random gathers (L2-miss -> L3 latency exposed); this trades
//     VGPRs (~100) for ~48 outstanding loads/wave.

#define NNODES 50000
#define DEG    16
#define FD     128

#define NEG_LOG2E -1.44269504f

typedef __bf16 bf16x8 __attribute__((ext_vector_type(8)));
typedef short  s16x8  __attribute__((ext_vector_type(8)));
typedef float  f32x4  __attribute__((ext_vector_type(4)));
typedef float  f32x2  __attribute__((ext_vector_type(2)));

__device__ __forceinline__ short f2bf_s(float f) {
    union { float f; uint32_t u; } v; v.f = f;
    uint32_t r = v.u + 0x7fffu + ((v.u >> 16) & 1u);   // RNE
    return (short)(r >> 16);
}
__device__ __forceinline__ float bflo(uint32_t u) {
    union { uint32_t u; float f; } v; v.u = u << 16;
    return v.f;
}
__device__ __forceinline__ float bfhi(uint32_t u) {
    union { uint32_t u; float f; } v; v.u = u & 0xffff0000u;
    return v.f;
}

// Pack Wmb[k][c] (c<128: Wm_top; c>=128: Wm_bot), PRE-SCALED by -log2e, and weight
// (unscaled) into bf16 B-fragment order: idx = ((kk*NT+ntile)*64 + q*16 + n15)*8 + (k&7).
__global__ __launch_bounds__(256) void pack_k(const float* __restrict__ wm,
                                              const float* __restrict__ w,
                                              short* __restrict__ wmb,
                                              short* __restrict__ wpack) {
    int tid = blockIdx.x * 256 + threadIdx.x;
    if (tid < 128 * 256) {
        int k = tid >> 8, c = tid & 255;
        float v = (c < 128) ? wm[k * 128 + c] : wm[(128 + k) * 128 + (c - 128)];
        int idx = (((k >> 5) * 16 + (c >> 4)) * 64 + ((k >> 3) & 3) * 16 + (c & 15)) * 8 + (k & 7);
        wmb[idx] = f2bf_s(NEG_LOG2E * v);
    }
    if (tid < 128 * 128) {
        int k = tid >> 7, n = tid & 127;
        int idx = (((k >> 5) * 8 + (n >> 4)) * 64 + ((k >> 3) & 3) * 16 + (n & 15)) * 8 + (k & 7);
        wpack[idx] = f2bf_s(w[tid]);
    }
}

// ZY' = x @ Wmb' ([50000x128]@[128x256]). Block = 16 nodes, 4 waves.
// Epilogue via LDS transpose, coalesced writes:
//   c<128  -> zbf bf16 pairs (z' rows)
//   c>=128 -> xb bf16 pairs (x rows, 256 B) + y8 fp8 (y' rows, 128 B)
__global__ __launch_bounds__(256) void zy_k(const float* __restrict__ x,
                                            const short* __restrict__ wmb,
                                            short* __restrict__ zbf,
                                            uint32_t* __restrict__ xb,
                                            uint8_t* __restrict__ y8) {
    __shared__ float ct[16 * 260];
    const int tid = threadIdx.x, wave = tid >> 6, lane = tid & 63;
    const int q = lane >> 4, m = lane & 15;
    const int node0 = blockIdx.x * 16;

    f32x4 acc[4];
    #pragma unroll
    for (int nt = 0; nt < 4; ++nt) acc[nt] = (f32x4){0.f, 0.f, 0.f, 0.f};

    #pragma unroll
    for (int kk = 0; kk < 4; ++kk) {
        const float* rp = x + (size_t)(node0 + m) * FD + kk * 32 + q * 8;
        f32x4 lo = *reinterpret_cast<const f32x4*>(rp);
        f32x4 hi = *reinterpret_cast<const f32x4*>(rp + 4);
        bf16x8 a;
        a[0]=(__bf16)lo.x; a[1]=(__bf16)lo.y; a[2]=(__bf16)lo.z; a[3]=(__bf16)lo.w;
        a[4]=(__bf16)hi.x; a[5]=(__bf16)hi.y; a[6]=(__bf16)hi.z; a[7]=(__bf16)hi.w;
        #pragma unroll
        for (int nt = 0; nt < 4; ++nt) {
            int frag = kk * 16 + wave * 4 + nt;
            s16x8 braw = *reinterpret_cast<const s16x8*>(wmb + ((size_t)frag * 64 + lane) * 8);
            acc[nt] = __builtin_amdgcn_mfma_f32_16x16x32_bf16(a, __builtin_bit_cast(bf16x8, braw), acc[nt], 0, 0, 0);
        }
    }
    #pragma unroll
    for (int nt = 0; nt < 4; ++nt)
        #pragma unroll
        for (int i = 0; i < 4; ++i)
            ct[(q * 4 + i) * 260 + wave * 64 + nt * 16 + m] = acc[nt][i];
    __syncthreads();

    const int row = tid >> 4;                 // 0..15
    const int c0  = (tid & 15) * 16;          // 0..240
    const int grow = node0 + row;
    if (c0 < 128) {
        uint32_t zo[8];
        #pragma unroll
        for (int j = 0; j < 8; ++j) {
            float v0 = ct[row * 260 + c0 + 2 * j];
            float v1 = ct[row * 260 + c0 + 2 * j + 1];
            zo[j] = (uint32_t)(uint16_t)f2bf_s(v0) | ((uint32_t)(uint16_t)f2bf_s(v1) << 16);
        }
        uint4* dst = reinterpret_cast<uint4*>(zbf + (size_t)grow * FD + c0);
        dst[0] = make_uint4(zo[0], zo[1], zo[2], zo[3]);
        dst[1] = make_uint4(zo[4], zo[5], zo[6], zo[7]);
    } else {
        const int f0 = c0 - 128;
        const float* xr = x + (size_t)grow * FD + f0;   // L1-hot
        // x -> bf16 pairs (8 uints)
        uint32_t xo[8];
        #pragma unroll
        for (int j = 0; j < 8; ++j) {
            float v0 = xr[2 * j], v1 = xr[2 * j + 1];
            xo[j] = (uint32_t)(uint16_t)f2bf_s(v0) | ((uint32_t)(uint16_t)f2bf_s(v1) << 16);
        }
        uint4* xdst = reinterpret_cast<uint4*>(xb + (size_t)grow * 64 + f0 / 2);
        xdst[0] = make_uint4(xo[0], xo[1], xo[2], xo[3]);
        xdst[1] = make_uint4(xo[4], xo[5], xo[6], xo[7]);
        // y' -> fp8 (16 bytes = 4 dwords)
        uint32_t yo[4];
        #pragma unroll
        for (int g = 0; g < 4; ++g) {
            float y0 = ct[row * 260 + c0 + 4 * g];
            float y1 = ct[row * 260 + c0 + 4 * g + 1];
            float y2 = ct[row * 260 + c0 + 4 * g + 2];
            float y3 = ct[row * 260 + c0 + 4 * g + 3];
            int u = __builtin_amdgcn_cvt_pk_fp8_f32(y0, y1, 0, false);
            u     = __builtin_amdgcn_cvt_pk_fp8_f32(y2, y3, u, true);
            yo[g] = (uint32_t)u;
        }
        *reinterpret_cast<uint4*>(y8 + (size_t)grow * 128 + f0) = make_uint4(yo[0], yo[1], yo[2], yo[3]);
    }
}

// Pure gather+sigmoid (no LDS/barrier). Block = 4 waves x 4 nodes; lane owns features
// 2*lane, 2*lane+1. R9: load-all-then-compute — all 32 xb + 32 y8 gathers for a node
// pair issued into register arrays before the sigmoid/FMA loop consumes them.
// x_new = x + sum_e sigmoid(z'+y'[src])*x[src] -> xnb bf16 rows (256 B, coalesced).
__global__ __launch_bounds__(256) void edge_k(const short* __restrict__ zbf,
                                              const uint32_t* __restrict__ xb,
                                              const uint8_t* __restrict__ y8,
                                              const int* __restrict__ esrc,
                                              uint32_t* __restrict__ xnb) {
    const int tid = threadIdx.x, wave = tid >> 6, lane = tid & 63;
    const int wn0 = blockIdx.x * 16 + wave * 4;

    #pragma unroll 1
    for (int pr = 0; pr < 2; ++pr) {
        const int nuA = __builtin_amdgcn_readfirstlane(wn0 + pr * 2);
        const int nuB = nuA + 1;                       // uniform
        const int* epA = esrc + nuA * DEG;             // uniform -> s_load_dwordx16
        const int* epB = esrc + nuB * DEG;
        int sA[16], sB[16];
        #pragma unroll
        for (int e = 0; e < 16; ++e) { sA[e] = epA[e]; sB[e] = epB[e]; }

        uint32_t zA = reinterpret_cast<const uint32_t*>(zbf + (size_t)nuA * FD)[lane];
        uint32_t zB = reinterpret_cast<const uint32_t*>(zbf + (size_t)nuB * FD)[lane];
        uint32_t cAw = xb[(size_t)nuA * 64 + lane];
        uint32_t cBw = xb[(size_t)nuB * 64 + lane];

        // Issue ALL gathers (static indices -> stays in VGPRs, no scratch).
        uint32_t xA[16], xB[16];
        uint16_t yA[16], yB[16];
        #pragma unroll
        for (int e = 0; e < 16; ++e) {
            xA[e] = xb[(size_t)sA[e] * 64 + lane];
            xB[e] = xb[(size_t)sB[e] * 64 + lane];
            yA[e] = *reinterpret_cast<const uint16_t*>(y8 + (size_t)sA[e] * 128 + 2 * lane);
            yB[e] = *reinterpret_cast<const uint16_t*>(y8 + (size_t)sB[e] * 128 + 2 * lane);
        }

        const float zA0 = bflo(zA), zA1 = bfhi(zA);
        const float zB0 = bflo(zB), zB1 = bfhi(zB);
        float aA0 = 0.f, aA1 = 0.f, bA0 = 0.f, bA1 = 0.f;
        float aB0 = 0.f, aB1 = 0.f, bB0 = 0.f, bB1 = 0.f;
        #pragma unroll
        for (int e = 0; e < 16; ++e) {
            f32x2 pA = __builtin_amdgcn_cvt_pk_f32_fp8((int)yA[e], false);   // (y'_{2l}, y'_{2l+1})
            f32x2 pB = __builtin_amdgcn_cvt_pk_f32_fp8((int)yB[e], false);
            float gA0 = __builtin_amdgcn_rcpf(1.f + __builtin_amdgcn_exp2f(zA0 + pA.x));
            float gA1 = __builtin_amdgcn_rcpf(1.f + __builtin_amdgcn_exp2f(zA1 + pA.y));
            float gB0 = __builtin_amdgcn_rcpf(1.f + __builtin_amdgcn_exp2f(zB0 + pB.x));
            float gB1 = __builtin_amdgcn_rcpf(1.f + __builtin_amdgcn_exp2f(zB1 + pB.y));
            if (e & 1) { bA0 += gA0 * bflo(xA[e]); bA1 += gA1 * bfhi(xA[e]); bB0 += gB0 * bflo(xB[e]); bB1 += gB1 * bfhi(xB[e]); }
            else       { aA0 += gA0 * bflo(xA[e]); aA1 += gA1 * bfhi(xA[e]); aB0 += gB0 * bflo(xB[e]); aB1 += gB1 * bfhi(xB[e]); }
        }
        float xA0 = bflo(cAw) + aA0 + bA0, xA1 = bfhi(cAw) + aA1 + bA1;
        float xB0 = bflo(cBw) + aB0 + bB0, xB1 = bfhi(cBw) + aB1 + bB1;
        xnb[(size_t)nuA * 64 + lane] = (uint32_t)(uint16_t)f2bf_s(xA0) | ((uint32_t)(uint16_t)f2bf_s(xA1) << 16);
        xnb[(size_t)nuB * 64 + lane] = (uint32_t)(uint16_t)f2bf_s(xB0) | ((uint32_t)(uint16_t)f2bf_s(xB1) << 16);
    }
}

// out = (sum_e adj*x_new[src]) @ weight + bias. Block = 16 nodes, 4 waves x 4 nodes.
// Phase A: adj-weighted gather of x_new bf16 rows -> xn LDS (R9: load-all-then-compute).
// Phase B: [16x128]@[128x128] MFMA with fused bias.
__global__ __launch_bounds__(256) void out_k(const uint32_t* __restrict__ xnb,
                                             const float* __restrict__ adj,
                                             const int* __restrict__ esrc,
                                             const short* __restrict__ wpack,
                                             const float* __restrict__ bias,
                                             float* __restrict__ out) {
    __shared__ float xn[16 * 132];
    const int tid = threadIdx.x, wave = tid >> 6, lane = tid & 63;
    const int q = lane >> 4, m = lane & 15;
    const int node0 = blockIdx.x * 16;
    const int wn0 = node0 + wave * 4;

    #pragma unroll 1
    for (int pr = 0; pr < 2; ++pr) {
        const int nuA = __builtin_amdgcn_readfirstlane(wn0 + pr * 2);
        const int nuB = nuA + 1;                       // uniform
        const int* epA = esrc + nuA * DEG;
        const int* epB = esrc + nuB * DEG;
        const float* apA = adj + nuA * DEG;
        const float* apB = adj + nuB * DEG;
        int sA[16], sB[16];
        #pragma unroll
        for (int e = 0; e < 16; ++e) { sA[e] = epA[e]; sB[e] = epB[e]; }
        float wAv[16], wBv[16];
        #pragma unroll
        for (int e = 0; e < 16; ++e) { wAv[e] = apA[e]; wBv[e] = apB[e]; }

        uint32_t uA[16], uB[16];
        #pragma unroll
        for (int e = 0; e < 16; ++e) {
            uA[e] = xnb[(size_t)sA[e] * 64 + lane];
            uB[e] = xnb[(size_t)sB[e] * 64 + lane];
        }

        float aA0 = 0.f, aA1 = 0.f, bA0 = 0.f, bA1 = 0.f;
        float aB0 = 0.f, aB1 = 0.f, bB0 = 0.f, bB1 = 0.f;
        #pragma unroll
        for (int e = 0; e < 16; ++e) {
            float wA = wAv[e], wB = wBv[e];
            if (e & 1) { bA0 += wA * bflo(uA[e]); bA1 += wA * bfhi(uA[e]); bB0 += wB * bflo(uB[e]); bB1 += wB * bfhi(uB[e]); }
            else       { aA0 += wA * bflo(uA[e]); aA1 += wA * bfhi(uA[e]); aB0 += wB * bflo(uB[e]); aB1 += wB * bfhi(uB[e]); }
        }
        const int rA = wave * 4 + pr * 2, rB = rA + 1;
        f32x2 tA; tA.x = aA0 + bA0; tA.y = aA1 + bA1;
        f32x2 tB; tB.x = aB0 + bB0; tB.y = aB1 + bB1;
        *reinterpret_cast<f32x2*>(&xn[rA * 132 + 2 * lane]) = tA;
        *reinterpret_cast<f32x2*>(&xn[rB * 132 + 2 * lane]) = tB;
    }
    __syncthreads();

    f32x4 sacc[2];
    sacc[0] = (f32x4){0.f, 0.f, 0.f, 0.f};
    sacc[1] = (f32x4){0.f, 0.f, 0.f, 0.f};
    #pragma unroll
    for (int kk = 0; kk < 4; ++kk) {
        const float* p = &xn[m * 132 + kk * 32 + q * 8];
        bf16x8 a;
        a[0]=(__bf16)p[0]; a[1]=(__bf16)p[1]; a[2]=(__bf16)p[2]; a[3]=(__bf16)p[3];
        a[4]=(__bf16)p[4]; a[5]=(__bf16)p[5]; a[6]=(__bf16)p[6]; a[7]=(__bf16)p[7];
        #pragma unroll
        for (int t = 0; t < 2; ++t) {
            int nt = wave * 2 + t;
            s16x8 braw = *reinterpret_cast<const s16x8*>(wpack + ((size_t)(kk * 8 + nt) * 64 + lane) * 8);
            sacc[t] = __builtin_amdgcn_mfma_f32_16x16x32_bf16(a, __builtin_bit_cast(bf16x8, braw), sacc[t], 0, 0, 0);
        }
    }
    #pragma unroll
    for (int t = 0; t < 2; ++t) {
        const int f = (wave * 2 + t) * 16 + m;
        const float bv = bias[f];
        #pragma unroll
        for (int i = 0; i < 4; ++i)
            out[(size_t)(node0 + q * 4 + i) * FD + f] = sacc[t][i] + bv;
    }
}

extern "C" void kernel_launch(void* const* d_in, const int* in_sizes, int n_in,
                              void* d_out, int out_size, void* d_ws, size_t ws_size,
                              hipStream_t stream) {
    const float* x      = (const float*)d_in[0];
    const float* weight = (const float*)d_in[1];
    const float* bias   = (const float*)d_in[2];
    const float* wm     = (const float*)d_in[3];
    const float* adj    = (const float*)d_in[4];
    const int*   esrc   = (const int*)d_in[5];
    // d_in[6] edge_dst unused: dst(e) = e/16 by construction.

    // ws: [0,64K) wmb | [64K,96K) wpack | [96K,+12.8M) zbf | [+12.8M,+25.6M) xnb.
    // d_out scratch phase: [0,12.8M) xb (bf16 x rows) | [12.8M,+6.4M) y8 (fp8 y' rows);
    // both fully consumed by edge_k before out_k overwrites d_out with the real output.
    short*    wmb   = (short*)d_ws;
    short*    wpack = (short*)((char*)d_ws + 65536);
    short*    zbf   = (short*)((char*)d_ws + 98304);
    uint32_t* xnb   = (uint32_t*)((char*)d_ws + 98304 + (size_t)NNODES * FD * 2);
    uint32_t* xb    = (uint32_t*)d_out;
    uint8_t*  y8    = (uint8_t*)d_out + (size_t)NNODES * FD * 2;
    float*    out   = (float*)d_out;

    pack_k <<<128,         256, 0, stream>>>(wm, weight, wmb, wpack);
    zy_k   <<<NNODES / 16, 256, 0, stream>>>(x, wmb, zbf, xb, y8);
    edge_k <<<NNODES / 16, 256, 0, stream>>>(zbf, xb, y8, esrc, xnb);
    out_k  <<<NNODES / 16, 256, 0, stream>>>(xnb, adj, esrc, wpack, bias, out);
}

// Round 2
// 179.168 us; speedup vs baseline: 1.0099x; 1.0099x over previous
//
#include <hip/hip_runtime.h>
#include <stdint.h>
#include <stddef.h>

// gcnmask: N=50000, DEG=16, F=128. Edges grouped by dst (dst = e/16) -> no atomics.
// R10: trans-op hoist. y8 now stores E = exp2(y'_scaled) in fp8 (computed once per src
//      node in zy_k) instead of y'. edge_k computes g = rcp(fma(Ez, E, 1)) with
//      Ez = exp2(z') hoisted per dst node: per-edge trans ops drop 4 -> 2 and two adds
//      disappear (800K*128 exp2 -> 50K*128). R8/R9 showed edge_k is ~half VALU-bound
//      (VALUBusy 54% = 24us of 44.8us) and MLP-restructuring alone is neutral.

#define NNODES 50000
#define DEG    16
#define FD     128

#define NEG_LOG2E -1.44269504f

typedef __bf16 bf16x8 __attribute__((ext_vector_type(8)));
typedef short  s16x8  __attribute__((ext_vector_type(8)));
typedef float  f32x4  __attribute__((ext_vector_type(4)));
typedef float  f32x2  __attribute__((ext_vector_type(2)));

__device__ __forceinline__ short f2bf_s(float f) {
    union { float f; uint32_t u; } v; v.f = f;
    uint32_t r = v.u + 0x7fffu + ((v.u >> 16) & 1u);   // RNE
    return (short)(r >> 16);
}
__device__ __forceinline__ float bflo(uint32_t u) {
    union { uint32_t u; float f; } v; v.u = u << 16;
    return v.f;
}
__device__ __forceinline__ float bfhi(uint32_t u) {
    union { uint32_t u; float f; } v; v.u = u & 0xffff0000u;
    return v.f;
}

// Pack Wmb[k][c] (c<128: Wm_top; c>=128: Wm_bot), PRE-SCALED by -log2e, and weight
// (unscaled) into bf16 B-fragment order: idx = ((kk*NT+ntile)*64 + q*16 + n15)*8 + (k&7).
__global__ __launch_bounds__(256) void pack_k(const float* __restrict__ wm,
                                              const float* __restrict__ w,
                                              short* __restrict__ wmb,
                                              short* __restrict__ wpack) {
    int tid = blockIdx.x * 256 + threadIdx.x;
    if (tid < 128 * 256) {
        int k = tid >> 8, c = tid & 255;
        float v = (c < 128) ? wm[k * 128 + c] : wm[(128 + k) * 128 + (c - 128)];
        int idx = (((k >> 5) * 16 + (c >> 4)) * 64 + ((k >> 3) & 3) * 16 + (c & 15)) * 8 + (k & 7);
        wmb[idx] = f2bf_s(NEG_LOG2E * v);
    }
    if (tid < 128 * 128) {
        int k = tid >> 7, n = tid & 127;
        int idx = (((k >> 5) * 8 + (n >> 4)) * 64 + ((k >> 3) & 3) * 16 + (n & 15)) * 8 + (k & 7);
        wpack[idx] = f2bf_s(w[tid]);
    }
}

// ZY' = x @ Wmb' ([50000x128]@[128x256]). Block = 16 nodes, 4 waves.
// Epilogue via LDS transpose, coalesced writes:
//   c<128  -> zbf bf16 pairs (z' rows)
//   c>=128 -> xb bf16 pairs (x rows, 256 B) + y8 fp8 E-rows (E = exp2(y'), 128 B)
__global__ __launch_bounds__(256) void zy_k(const float* __restrict__ x,
                                            const short* __restrict__ wmb,
                                            short* __restrict__ zbf,
                                            uint32_t* __restrict__ xb,
                                            uint8_t* __restrict__ y8) {
    __shared__ float ct[16 * 260];
    const int tid = threadIdx.x, wave = tid >> 6, lane = tid & 63;
    const int q = lane >> 4, m = lane & 15;
    const int node0 = blockIdx.x * 16;

    f32x4 acc[4];
    #pragma unroll
    for (int nt = 0; nt < 4; ++nt) acc[nt] = (f32x4){0.f, 0.f, 0.f, 0.f};

    #pragma unroll
    for (int kk = 0; kk < 4; ++kk) {
        const float* rp = x + (size_t)(node0 + m) * FD + kk * 32 + q * 8;
        f32x4 lo = *reinterpret_cast<const f32x4*>(rp);
        f32x4 hi = *reinterpret_cast<const f32x4*>(rp + 4);
        bf16x8 a;
        a[0]=(__bf16)lo.x; a[1]=(__bf16)lo.y; a[2]=(__bf16)lo.z; a[3]=(__bf16)lo.w;
        a[4]=(__bf16)hi.x; a[5]=(__bf16)hi.y; a[6]=(__bf16)hi.z; a[7]=(__bf16)hi.w;
        #pragma unroll
        for (int nt = 0; nt < 4; ++nt) {
            int frag = kk * 16 + wave * 4 + nt;
            s16x8 braw = *reinterpret_cast<const s16x8*>(wmb + ((size_t)frag * 64 + lane) * 8);
            acc[nt] = __builtin_amdgcn_mfma_f32_16x16x32_bf16(a, __builtin_bit_cast(bf16x8, braw), acc[nt], 0, 0, 0);
        }
    }
    #pragma unroll
    for (int nt = 0; nt < 4; ++nt)
        #pragma unroll
        for (int i = 0; i < 4; ++i)
            ct[(q * 4 + i) * 260 + wave * 64 + nt * 16 + m] = acc[nt][i];
    __syncthreads();

    const int row = tid >> 4;                 // 0..15
    const int c0  = (tid & 15) * 16;          // 0..240
    const int grow = node0 + row;
    if (c0 < 128) {
        uint32_t zo[8];
        #pragma unroll
        for (int j = 0; j < 8; ++j) {
            float v0 = ct[row * 260 + c0 + 2 * j];
            float v1 = ct[row * 260 + c0 + 2 * j + 1];
            zo[j] = (uint32_t)(uint16_t)f2bf_s(v0) | ((uint32_t)(uint16_t)f2bf_s(v1) << 16);
        }
        uint4* dst = reinterpret_cast<uint4*>(zbf + (size_t)grow * FD + c0);
        dst[0] = make_uint4(zo[0], zo[1], zo[2], zo[3]);
        dst[1] = make_uint4(zo[4], zo[5], zo[6], zo[7]);
    } else {
        const int f0 = c0 - 128;
        const float* xr = x + (size_t)grow * FD + f0;   // L1-hot
        // x -> bf16 pairs (8 uints)
        uint32_t xo[8];
        #pragma unroll
        for (int j = 0; j < 8; ++j) {
            float v0 = xr[2 * j], v1 = xr[2 * j + 1];
            xo[j] = (uint32_t)(uint16_t)f2bf_s(v0) | ((uint32_t)(uint16_t)f2bf_s(v1) << 16);
        }
        uint4* xdst = reinterpret_cast<uint4*>(xb + (size_t)grow * 64 + f0 / 2);
        xdst[0] = make_uint4(xo[0], xo[1], xo[2], xo[3]);
        xdst[1] = make_uint4(xo[4], xo[5], xo[6], xo[7]);
        // E = exp2(y') -> fp8 (16 bytes = 4 dwords). cvt_pk_fp8 saturates to +-448;
        // exp2 overflow -> g ~ 1/449 (true g smaller), underflow -> 0 -> g = 1. Both benign.
        uint32_t yo[4];
        #pragma unroll
        for (int g = 0; g < 4; ++g) {
            float y0 = __builtin_amdgcn_exp2f(ct[row * 260 + c0 + 4 * g]);
            float y1 = __builtin_amdgcn_exp2f(ct[row * 260 + c0 + 4 * g + 1]);
            float y2 = __builtin_amdgcn_exp2f(ct[row * 260 + c0 + 4 * g + 2]);
            float y3 = __builtin_amdgcn_exp2f(ct[row * 260 + c0 + 4 * g + 3]);
            int u = __builtin_amdgcn_cvt_pk_fp8_f32(y0, y1, 0, false);
            u     = __builtin_amdgcn_cvt_pk_fp8_f32(y2, y3, u, true);
            yo[g] = (uint32_t)u;
        }
        *reinterpret_cast<uint4*>(y8 + (size_t)grow * 128 + f0) = make_uint4(yo[0], yo[1], yo[2], yo[3]);
    }
}

// Pure gather+sigmoid (no LDS/barrier). Block = 4 waves x 4 nodes; lane owns features
// 2*lane, 2*lane+1. Load-all-then-compute batches; per-edge math is now
// g = rcp(fma(Ez, E[src], 1)) with Ez = exp2(z') hoisted per node (2 trans/edge, was 4).
// x_new = x + sum_e g*x[src] -> xnb bf16 rows (256 B, coalesced).
__global__ __launch_bounds__(256) void edge_k(const short* __restrict__ zbf,
                                              const uint32_t* __restrict__ xb,
                                              const uint8_t* __restrict__ y8,
                                              const int* __restrict__ esrc,
                                              uint32_t* __restrict__ xnb) {
    const int tid = threadIdx.x, wave = tid >> 6, lane = tid & 63;
    const int wn0 = blockIdx.x * 16 + wave * 4;

    #pragma unroll 1
    for (int pr = 0; pr < 2; ++pr) {
        const int nuA = __builtin_amdgcn_readfirstlane(wn0 + pr * 2);
        const int nuB = nuA + 1;                       // uniform
        const int* epA = esrc + nuA * DEG;             // uniform -> s_load_dwordx16
        const int* epB = esrc + nuB * DEG;
        int sA[16], sB[16];
        #pragma unroll
        for (int e = 0; e < 16; ++e) { sA[e] = epA[e]; sB[e] = epB[e]; }

        uint32_t zA = reinterpret_cast<const uint32_t*>(zbf + (size_t)nuA * FD)[lane];
        uint32_t zB = reinterpret_cast<const uint32_t*>(zbf + (size_t)nuB * FD)[lane];
        uint32_t cAw = xb[(size_t)nuA * 64 + lane];
        uint32_t cBw = xb[(size_t)nuB * 64 + lane];

        // Issue ALL gathers (static indices -> stays in VGPRs, no scratch).
        uint32_t xA[16], xB[16];
        uint16_t yA[16], yB[16];
        #pragma unroll
        for (int e = 0; e < 16; ++e) {
            xA[e] = xb[(size_t)sA[e] * 64 + lane];
            xB[e] = xb[(size_t)sB[e] * 64 + lane];
            yA[e] = *reinterpret_cast<const uint16_t*>(y8 + (size_t)sA[e] * 128 + 2 * lane);
            yB[e] = *reinterpret_cast<const uint16_t*>(y8 + (size_t)sB[e] * 128 + 2 * lane);
        }

        const float EzA0 = __builtin_amdgcn_exp2f(bflo(zA)), EzA1 = __builtin_amdgcn_exp2f(bfhi(zA));
        const float EzB0 = __builtin_amdgcn_exp2f(bflo(zB)), EzB1 = __builtin_amdgcn_exp2f(bfhi(zB));
        float aA0 = 0.f, aA1 = 0.f, bA0 = 0.f, bA1 = 0.f;
        float aB0 = 0.f, aB1 = 0.f, bB0 = 0.f, bB1 = 0.f;
        #pragma unroll
        for (int e = 0; e < 16; ++e) {
            f32x2 pA = __builtin_amdgcn_cvt_pk_f32_fp8((int)yA[e], false);   // (E_{2l}, E_{2l+1})
            f32x2 pB = __builtin_amdgcn_cvt_pk_f32_fp8((int)yB[e], false);
            float gA0 = __builtin_amdgcn_rcpf(__builtin_fmaf(EzA0, pA.x, 1.f));
            float gA1 = __builtin_amdgcn_rcpf(__builtin_fmaf(EzA1, pA.y, 1.f));
            float gB0 = __builtin_amdgcn_rcpf(__builtin_fmaf(EzB0, pB.x, 1.f));
            float gB1 = __builtin_amdgcn_rcpf(__builtin_fmaf(EzB1, pB.y, 1.f));
            if (e & 1) { bA0 += gA0 * bflo(xA[e]); bA1 += gA1 * bfhi(xA[e]); bB0 += gB0 * bflo(xB[e]); bB1 += gB1 * bfhi(xB[e]); }
            else       { aA0 += gA0 * bflo(xA[e]); aA1 += gA1 * bfhi(xA[e]); aB0 += gB0 * bflo(xB[e]); aB1 += gB1 * bfhi(xB[e]); }
        }
        float xA0 = bflo(cAw) + aA0 + bA0, xA1 = bfhi(cAw) + aA1 + bA1;
        float xB0 = bflo(cBw) + aB0 + bB0, xB1 = bfhi(cBw) + aB1 + bB1;
        xnb[(size_t)nuA * 64 + lane] = (uint32_t)(uint16_t)f2bf_s(xA0) | ((uint32_t)(uint16_t)f2bf_s(xA1) << 16);
        xnb[(size_t)nuB * 64 + lane] = (uint32_t)(uint16_t)f2bf_s(xB0) | ((uint32_t)(uint16_t)f2bf_s(xB1) << 16);
    }
}

// out = (sum_e adj*x_new[src]) @ weight + bias. Block = 16 nodes, 4 waves x 4 nodes.
// Phase A: adj-weighted gather of x_new bf16 rows -> xn LDS (load-all-then-compute).
// Phase B: [16x128]@[128x128] MFMA with fused bias.
__global__ __launch_bounds__(256) void out_k(const uint32_t* __restrict__ xnb,
                                             const float* __restrict__ adj,
                                             const int* __restrict__ esrc,
                                             const short* __restrict__ wpack,
                                             const float* __restrict__ bias,
                                             float* __restrict__ out) {
    __shared__ float xn[16 * 132];
    const int tid = threadIdx.x, wave = tid >> 6, lane = tid & 63;
    const int q = lane >> 4, m = lane & 15;
    const int node0 = blockIdx.x * 16;
    const int wn0 = node0 + wave * 4;

    #pragma unroll 1
    for (int pr = 0; pr < 2; ++pr) {
        const int nuA = __builtin_amdgcn_readfirstlane(wn0 + pr * 2);
        const int nuB = nuA + 1;                       // uniform
        const int* epA = esrc + nuA * DEG;
        const int* epB = esrc + nuB * DEG;
        const float* apA = adj + nuA * DEG;
        const float* apB = adj + nuB * DEG;
        int sA[16], sB[16];
        #pragma unroll
        for (int e = 0; e < 16; ++e) { sA[e] = epA[e]; sB[e] = epB[e]; }
        float wAv[16], wBv[16];
        #pragma unroll
        for (int e = 0; e < 16; ++e) { wAv[e] = apA[e]; wBv[e] = apB[e]; }

        uint32_t uA[16], uB[16];
        #pragma unroll
        for (int e = 0; e < 16; ++e) {
            uA[e] = xnb[(size_t)sA[e] * 64 + lane];
            uB[e] = xnb[(size_t)sB[e] * 64 + lane];
        }

        float aA0 = 0.f, aA1 = 0.f, bA0 = 0.f, bA1 = 0.f;
        float aB0 = 0.f, aB1 = 0.f, bB0 = 0.f, bB1 = 0.f;
        #pragma unroll
        for (int e = 0; e < 16; ++e) {
            float wA = wAv[e], wB = wBv[e];
            if (e & 1) { bA0 += wA * bflo(uA[e]); bA1 += wA * bfhi(uA[e]); bB0 += wB * bflo(uB[e]); bB1 += wB * bfhi(uB[e]); }
            else       { aA0 += wA * bflo(uA[e]); aA1 += wA * bfhi(uA[e]); aB0 += wB * bflo(uB[e]); aB1 += wB * bfhi(uB[e]); }
        }
        const int rA = wave * 4 + pr * 2, rB = rA + 1;
        f32x2 tA; tA.x = aA0 + bA0; tA.y = aA1 + bA1;
        f32x2 tB; tB.x = aB0 + bB0; tB.y = aB1 + bB1;
        *reinterpret_cast<f32x2*>(&xn[rA * 132 + 2 * lane]) = tA;
        *reinterpret_cast<f32x2*>(&xn[rB * 132 + 2 * lane]) = tB;
    }
    __syncthreads();

    f32x4 sacc[2];
    sacc[0] = (f32x4){0.f, 0.f, 0.f, 0.f};
    sacc[1] = (f32x4){0.f, 0.f, 0.f, 0.f};
    #pragma unroll
    for (int kk = 0; kk < 4; ++kk) {
        const float* p = &xn[m * 132 + kk * 32 + q * 8];
        bf16x8 a;
        a[0]=(__bf16)p[0]; a[1]=(__bf16)p[1]; a[2]=(__bf16)p[2]; a[3]=(__bf16)p[3];
        a[4]=(__bf16)p[4]; a[5]=(__bf16)p[5]; a[6]=(__bf16)p[6]; a[7]=(__bf16)p[7];
        #pragma unroll
        for (int t = 0; t < 2; ++t) {
            int nt = wave * 2 + t;
            s16x8 braw = *reinterpret_cast<const s16x8*>(wpack + ((size_t)(kk * 8 + nt) * 64 + lane) * 8);
            sacc[t] = __builtin_amdgcn_mfma_f32_16x16x32_bf16(a, __builtin_bit_cast(bf16x8, braw), sacc[t], 0, 0, 0);
        }
    }
    #pragma unroll
    for (int t = 0; t < 2; ++t) {
        const int f = (wave * 2 + t) * 16 + m;
        const float bv = bias[f];
        #pragma unroll
        for (int i = 0; i < 4; ++i)
            out[(size_t)(node0 + q * 4 + i) * FD + f] = sacc[t][i] + bv;
    }
}

extern "C" void kernel_launch(void* const* d_in, const int* in_sizes, int n_in,
                              void* d_out, int out_size, void* d_ws, size_t ws_size,
                              hipStream_t stream) {
    const float* x      = (const float*)d_in[0];
    const float* weight = (const float*)d_in[1];
    const float* bias   = (const float*)d_in[2];
    const float* wm     = (const float*)d_in[3];
    const float* adj    = (const float*)d_in[4];
    const int*   esrc   = (const int*)d_in[5];
    // d_in[6] edge_dst unused: dst(e) = e/16 by construction.

    // ws: [0,64K) wmb | [64K,96K) wpack | [96K,+12.8M) zbf | [+12.8M,+25.6M) xnb.
    // d_out scratch phase: [0,12.8M) xb (bf16 x rows) | [12.8M,+6.4M) y8 (fp8 E rows);
    // both fully consumed by edge_k before out_k overwrites d_out with the real output.
    short*    wmb   = (short*)d_ws;
    short*    wpack = (short*)((char*)d_ws + 65536);
    short*    zbf   = (short*)((char*)d_ws + 98304);
    uint32_t* xnb   = (uint32_t*)((char*)d_ws + 98304 + (size_t)NNODES * FD * 2);
    uint32_t* xb    = (uint32_t*)d_out;
    uint8_t*  y8    = (uint8_t*)d_out + (size_t)NNODES * FD * 2;
    float*    out   = (float*)d_out;

    pack_k <<<128,         256, 0, stream>>>(wm, weight, wmb, wpack);
    zy_k   <<<NNODES / 16, 256, 0, stream>>>(x, wmb, zbf, xb, y8);
    edge_k <<<NNODES / 16, 256, 0, stream>>>(zbf, xb, y8, esrc, xnb);
    out_k  <<<NNODES / 16, 256, 0, stream>>>(xnb, adj, esrc, wpack, bias, out);
}